// Round 15
// baseline (1361.483 us; speedup 1.0000x reference)
//
#include <hip/hip_runtime.h>
#include <stdint.h>

// ======== DIAGNOSTIC ROUND #2 on the R14 champion (156 us): each kernel
// repeats its idempotent body R times so every dispatch exceeds the ~165us
// poison-fill floor and surfaces in rocprof top-5 with its counters.
// Per-iteration code byte-identical to R14.
#define R_CSR   24
#define R_SCORE 4
#define R_TOPK  16
#define R_FEAT  24
#define R_SM    10
#define KEEP() asm volatile("" ::: "memory")

// Problem constants (from reference setup_inputs)
#define Bg    128
#define NPG   512
#define Cc    128
#define EPG   8192
#define Nn    (Bg*NPG)      // 65536
#define Ee    (Bg*EPG)      // 1048576
#define Kk    410           // ceil(0.8*512)
#define NKk   (Bg*Kk)       // 52480
#define ROFFS_STRIDE 411
#define SLOPE 0.2f
#define GPB   103

typedef float f2v __attribute__((ext_vector_type(2)));

// ---------- LDS exclusive scan over 512 ints, 512 threads ----------
__device__ __forceinline__ void scan512(int* buf, int* ws) {
  int t = threadIdx.x, lane = t & 63, w = t >> 6;
  int v = buf[t];
  int s = v;
  #pragma unroll
  for (int d = 1; d < 64; d <<= 1) { int u = __shfl_up(s, d, 64); if (lane >= d) s += u; }
  if (lane == 63) ws[w] = s;
  __syncthreads();
  if (t < 8) {
    int u = ws[t];
    #pragma unroll
    for (int d = 1; d < 8; d <<= 1) { int u2 = __shfl_up(u, d, 64); if (t >= d) u += u2; }
    ws[t] = u;
  }
  __syncthreads();
  int excl = s - v + (w ? ws[w - 1] : 0);
  buf[t] = excl;
  __syncthreads();
}

// ---------- K1: per-graph {deg, dis, count, scan, packed dst-CSR} ----------
__global__ __launch_bounds__(512) void k_build_csr(const int* __restrict__ row,
                                                   const int* __restrict__ col,
                                                   const float* __restrict__ attr,
                                                   int* __restrict__ offs,
                                                   int2* __restrict__ csrp) {
  __shared__ int cnt[512];
  __shared__ int cur[512];
  __shared__ float degL[512];
  __shared__ float disL[512];
  __shared__ int ws[8];
  int bb = blockIdx.x;
  int g = (bb & 7) * 16 + (bb >> 3);
  int t = threadIdx.x, base = g * NPG;
  const int*   rowg  = row  + g * EPG;
  const int*   colg  = col  + g * EPG;
  const float* attrg = attr + g * EPG;
  for (int rep = 0; rep < R_CSR; ++rep) {
    cnt[t] = 0; degL[t] = 0.f;
    __syncthreads();
    for (int i = t; i < EPG; i += 512) {
      atomicAdd(&cnt[colg[i] - base], 1);
      atomicAdd(&degL[rowg[i] - base], attrg[i]);
    }
    __syncthreads();
    float d = degL[t];
    disL[t] = (d > 0.f) ? rsqrtf(fmaxf(d, 1e-12f)) : 0.f;
    scan512(cnt, ws);
    offs[base + t] = g * EPG + cnt[t];
    if (t == 0) offs[base + NPG] = g * EPG + EPG;
    cur[t] = cnt[t];
    __syncthreads();
    for (int i = t; i < EPG; i += 512) {
      int s = rowg[i] - base, c = colg[i] - base;
      int slot = atomicAdd(&cur[c], 1);
      int2 p;
      p.x = rowg[i] << 9;
      p.y = __float_as_int(disL[s] * attrg[i] * disL[c]);
      csrp[g * EPG + slot] = p;
    }
    __syncthreads();
    KEEP();
  }
}

// ---------- K2: score gather + new_row/new_col streaming fill ----------
__global__ __launch_bounds__(256) void k_score(const float* __restrict__ x,
                                               const int* __restrict__ offs,
                                               const int2* __restrict__ csrp,
                                               float* __restrict__ score,
                                               float* __restrict__ nrow,
                                               float* __restrict__ ncol) {
  int bb = blockIdx.x;
  int lane = threadIdx.x & 63;
  int w4 = threadIdx.x >> 6;
  for (int rep = 0; rep < R_SCORE; ++rep) {
    int wid = bb * 4 + w4;
    if (wid < NKk) {
      int b = wid / Kk;
      float frow  = (float)wid;
      float cbase = (float)(b * Kk);
      size_t fb = (size_t)wid * Kk;
      f2v* nr = (f2v*)(nrow + fb);
      f2v* nc = (f2v*)(ncol + fb);
      for (int p = lane; p < Kk / 2; p += 64) {
        int j = 2 * p;
        f2v rv; rv.x = frow; rv.y = frow;
        f2v cv; cv.x = cbase + j; cv.y = cbase + j + 1;
        __builtin_nontemporal_store(rv, nr + p);
        __builtin_nontemporal_store(cv, nc + p);
      }
    }
    int wg = ((bb & 7) << 11) | (bb >> 3);
    int node = wg * 4 + w4;
    const char* xb = (const char*)x;
    int lo8 = lane * 8;
    float2 xv = *(const float2*)(xb + ((size_t)node << 9) + lo8);
    int s0 = offs[node], s1 = offs[node + 1];
    float a0 = 0.f, a1 = 0.f, b0 = 0.f, b1 = 0.f;
    int s = s0;
    for (; s + 4 <= s1; s += 4) {
      int2 p0 = csrp[s], p1 = csrp[s+1], p2 = csrp[s+2], p3 = csrp[s+3];
      float2 v0 = *(const float2*)(xb + p0.x + lo8);
      float2 v1 = *(const float2*)(xb + p1.x + lo8);
      float2 v2 = *(const float2*)(xb + p2.x + lo8);
      float2 v3 = *(const float2*)(xb + p3.x + lo8);
      float c0 = __int_as_float(p0.y), c1 = __int_as_float(p1.y);
      float c2 = __int_as_float(p2.y), c3 = __int_as_float(p3.y);
      a0 += c0 * v0.x; a1 += c0 * v0.y;
      b0 += c1 * v1.x; b1 += c1 * v1.y;
      a0 += c2 * v2.x; a1 += c2 * v2.y;
      b0 += c3 * v3.x; b1 += c3 * v3.y;
    }
    for (; s < s1; ++s) {
      int2 p0 = csrp[s];
      float2 v0 = *(const float2*)(xb + p0.x + lo8);
      float c0 = __int_as_float(p0.y);
      a0 += c0 * v0.x; a1 += c0 * v0.y;
    }
    float v = fabsf(xv.x - a0 - b0) + fabsf(xv.y - a1 - b1);
    #pragma unroll
    for (int d = 32; d; d >>= 1) v += __shfl_xor(v, d, 64);
    if (lane == 0) score[node] = v;
    KEEP();
  }
}

// ---------- K3: per-graph {stable top-k bitonic, perm/batch, induced CSR} ----------
__global__ __launch_bounds__(512) void k_topk_induced(const float* __restrict__ score,
                                                      const int* __restrict__ row,
                                                      const int* __restrict__ col,
                                                      const float* __restrict__ attr,
                                                      int* __restrict__ perm,
                                                      float* __restrict__ batch_out,
                                                      int* __restrict__ roffs,
                                                      int* __restrict__ icol,
                                                      float* __restrict__ ival) {
  __shared__ unsigned long long keys[512];
  __shared__ int mapL[512];
  __shared__ int rcnt[512];
  __shared__ int rcur[512];
  __shared__ int ws[8];
  int bb = blockIdx.x;
  int g = (bb & 7) * 16 + (bb >> 3);
  int t = threadIdx.x, base = g * NPG;
  const int*   rowg  = row  + g * EPG;
  const int*   colg  = col  + g * EPG;
  const float* attrg = attr + g * EPG;
  for (int rep = 0; rep < R_TOPK; ++rep) {
    float sc = score[base + t];
    unsigned u = __float_as_uint(sc);
    unsigned ord = (u & 0x80000000u) ? ~u : (u | 0x80000000u);
    keys[t] = ((unsigned long long)(~ord) << 32) | (unsigned)t;
    for (int k2 = 2; k2 <= 512; k2 <<= 1) {
      for (int j2 = k2 >> 1; j2 > 0; j2 >>= 1) {
        __syncthreads();
        int ixj = t ^ j2;
        if (ixj > t) {
          unsigned long long a = keys[t], b = keys[ixj];
          bool up = ((t & k2) == 0);
          if ((a > b) == up) { keys[t] = b; keys[ixj] = a; }
        }
      }
    }
    __syncthreads();
    int local = (int)(keys[t] & 0xFFFFFFFFu);
    mapL[local] = (t < Kk) ? t : -1;
    if (t < Kk) {
      perm[g * Kk + t] = base + local;
      batch_out[g * Kk + t] = (float)g;
    }
    rcnt[t] = 0;
    __syncthreads();
    for (int i = t; i < EPG; i += 512) {
      int mr = mapL[rowg[i] - base], mc = mapL[colg[i] - base];
      if (mr >= 0 && mc >= 0) atomicAdd(&rcnt[mr], 1);
    }
    __syncthreads();
    scan512(rcnt, ws);
    if (t <= Kk) roffs[g * ROFFS_STRIDE + t] = g * EPG + rcnt[t];
    rcur[t] = rcnt[t];
    __syncthreads();
    for (int i = t; i < EPG; i += 512) {
      int mr = mapL[rowg[i] - base], mc = mapL[colg[i] - base];
      if (mr >= 0 && mc >= 0) {
        int slot = atomicAdd(&rcur[mr], 1);
        icol[g * EPG + slot] = mc;
        ival[g * EPG + slot] = attrg[i];
      }
    }
    __syncthreads();
    KEEP();
  }
}

// ---------- K4: x_pool gather + e1/e2 GEMV, graph-aligned blocks ----------
__global__ __launch_bounds__(256) void k_feat(const float* __restrict__ x,
                                              const int* __restrict__ perm,
                                              const float* __restrict__ att,
                                              float* __restrict__ e1,
                                              float* __restrict__ e2,
                                              float* __restrict__ xpool) {
  int bb = blockIdx.x;
  int x8 = bb & 7, q = bb >> 3;
  int g = x8 * 16 + q / GPB;
  int blk = q % GPB;
  int lane = threadIdx.x & 63, w = threadIdx.x >> 6;
  int r = blk * 4 + w;
  if (r >= Kk) return;
  for (int rep = 0; rep < R_FEAT; ++rep) {
    int j = g * Kk + r;
    int gsrc = perm[j];
    float2 xv = ((const float2*)x)[(size_t)gsrc * 64 + lane];
    ((float2*)xpool)[(size_t)j * 64 + lane] = xv;
    float2 a1 = ((const float2*)att)[lane];
    float2 a2 = ((const float2*)(att + Cc))[lane];
    float s1 = xv.x * a1.x + xv.y * a1.y;
    float s2 = xv.x * a2.x + xv.y * a2.y;
    #pragma unroll
    for (int d = 32; d; d >>= 1) { s1 += __shfl_xor(s1, d, 64); s2 += __shfl_xor(s2, d, 64); }
    if (lane == 0) { e1[j] = s1; e2[j] = s2; }
    KEEP();
  }
}

// ---------- K5: softmax, graph-aligned blocks, e2 in LDS, attn-only stores ----------
__global__ __launch_bounds__(256) void k_softmax(const float* __restrict__ e1,
                                                 const float* __restrict__ e2,
                                                 const int* __restrict__ roffs,
                                                 const int* __restrict__ icol,
                                                 const float* __restrict__ ival,
                                                 float* __restrict__ attn) {
  __shared__ float e2s[412];
  __shared__ float buf[4][416];
  int bb = blockIdx.x;
  int x8 = bb & 7, q = bb >> 3;
  int g = x8 * 16 + q / GPB;
  int blk = q % GPB;
  int t = threadIdx.x, lane = t & 63, w = t >> 6;
  for (int rep = 0; rep < R_SM; ++rep) {
    for (int i = t; i < Kk; i += 256) e2s[i] = e2[g * Kk + i];
    __syncthreads();
    int r = blk * 4 + w;
    if (r < Kk) {
      int rowid = g * Kk + r;
      float* bw = buf[w];
      float ev = e1[rowid];
      for (int j = lane; j < Kk; j += 64) {
        float v = ev + e2s[j];
        bw[j] = (v > 0.f) ? v : SLOPE * v;
      }
      int t0 = roffs[g * ROFFS_STRIDE + r], t1 = roffs[g * ROFFS_STRIDE + r + 1];
      for (int p = t0 + lane; p < t1; p += 64)
        atomicAdd(&bw[icol[p]], ival[p]);
      float m = -1e30f;
      for (int j = lane; j < Kk; j += 64) m = fmaxf(m, bw[j]);
      #pragma unroll
      for (int d = 32; d; d >>= 1) m = fmaxf(m, __shfl_xor(m, d, 64));
      float s = 0.f;
      for (int j = lane; j < Kk; j += 64) {
        float ex = __expf(bw[j] - m);
        bw[j] = ex;
        s += ex;
      }
      #pragma unroll
      for (int d = 32; d; d >>= 1) s += __shfl_xor(s, d, 64);
      float inv = 1.f / s;
      size_t fb = (size_t)rowid * Kk;
      f2v* ap = (f2v*)(attn + fb);
      for (int p = lane; p < Kk / 2; p += 64) {
        int j = 2 * p;
        f2v av; av.x = bw[j] * inv; av.y = bw[j + 1] * inv;
        __builtin_nontemporal_store(av, ap + p);
      }
    }
    __syncthreads();
    KEEP();
  }
}

// ---------------- host launch ----------------
extern "C" void kernel_launch(void* const* d_in, const int* in_sizes, int n_in,
                              void* d_out, int out_size, void* d_ws, size_t ws_size,
                              hipStream_t stream) {
  const float* x    = (const float*)d_in[0];
  const int*   row  = (const int*)d_in[1];
  const int*   col  = row + Ee;
  const float* attr = (const float*)d_in[2];
  const float* att  = (const float*)d_in[4];

  char* ws = (char*)d_ws;
  size_t off = 0;
  auto alloc = [&](size_t bytes) { char* p = ws + off; off = (off + bytes + 255) & ~(size_t)255; return p; };
  int*   offs     = (int*)  alloc((size_t)(Nn + 1) * 4);
  int2*  csrp     = (int2*) alloc((size_t)Ee * 8);
  float* score    = (float*)alloc((size_t)Nn * 4);
  int*   perm     = (int*)  alloc((size_t)NKk * 4);
  int*   roffs    = (int*)  alloc((size_t)Bg * ROFFS_STRIDE * 4);
  int*   icol     = (int*)  alloc((size_t)Ee * 4);
  float* ival     = (float*)alloc((size_t)Ee * 4);
  float* e1       = (float*)alloc((size_t)NKk * 4);
  float* e2       = (float*)alloc((size_t)NKk * 4);

  // output layout: x_pool | new_row | new_col | attn | batch_pool (all fp32)
  float* out      = (float*)d_out;
  float* o_xpool  = out;
  float* o_nrow   = o_xpool + (size_t)NKk * Cc;
  float* o_ncol   = o_nrow + (size_t)NKk * Kk;
  float* o_attn   = o_ncol + (size_t)NKk * Kk;
  float* o_batch  = o_attn + (size_t)NKk * Kk;

  k_build_csr  <<<Bg,       512, 0, stream>>>(row, col, attr, offs, csrp);
  k_score      <<<Nn / 4,   256, 0, stream>>>(x, offs, csrp, score, o_nrow, o_ncol);
  k_topk_induced<<<Bg,      512, 0, stream>>>(score, row, col, attr, perm, o_batch, roffs, icol, ival);
  k_feat       <<<Bg * GPB, 256, 0, stream>>>(x, perm, att, e1, e2, o_xpool);
  k_softmax    <<<Bg * GPB, 256, 0, stream>>>(e1, e2, roffs, icol, ival, o_attn);
}

// Round 16
// 158.407 us; speedup vs baseline: 8.5948x; 8.5948x over previous
//
#include <hip/hip_runtime.h>
#include <stdint.h>

// Problem constants (from reference setup_inputs)
#define Bg    128
#define NPG   512
#define Cc    128
#define EPG   8192
#define Nn    (Bg*NPG)      // 65536
#define Ee    (Bg*EPG)      // 1048576
#define Kk    410           // ceil(0.8*512)
#define NKk   (Bg*Kk)       // 52480
#define ROFFS_STRIDE 411
#define SLOPE 0.2f
#define GPB   103           // graph-aligned blocks per graph for feat/softmax

typedef float f2v __attribute__((ext_vector_type(2)));

// ---------- LDS exclusive scan over 512 ints, 512 threads ----------
__device__ __forceinline__ void scan512(int* buf, int* ws) {
  int t = threadIdx.x, lane = t & 63, w = t >> 6;
  int v = buf[t];
  int s = v;
  #pragma unroll
  for (int d = 1; d < 64; d <<= 1) { int u = __shfl_up(s, d, 64); if (lane >= d) s += u; }
  if (lane == 63) ws[w] = s;
  __syncthreads();
  if (t < 8) {
    int u = ws[t];
    #pragma unroll
    for (int d = 1; d < 8; d <<= 1) { int u2 = __shfl_up(u, d, 64); if (t >= d) u += u2; }
    ws[t] = u;
  }
  __syncthreads();
  int excl = s - v + (w ? ws[w - 1] : 0);
  buf[t] = excl;
  __syncthreads();
}

// ---------- K1: per-graph {deg, dis, count, scan, packed dst-CSR} ----------
// Grid 256: blocks 0..127 build CSR (one graph each, XCD-aligned remap);
// blocks 128..255 run on the otherwise-IDLE half of the machine and
// stream graph g's 256KB x-slice into that XCD's L2/L3 (g chosen so the
// prefetching block's XCD == the XCD score's swizzle assigns g's readers),
// killing score's cold-start HBM misses. Live scratch write prevents DCE.
__global__ __launch_bounds__(512) void k_build_csr(const int* __restrict__ row,
                                                   const int* __restrict__ col,
                                                   const float* __restrict__ attr,
                                                   const float* __restrict__ x,
                                                   int* __restrict__ offs,
                                                   int2* __restrict__ csrp,
                                                   float* __restrict__ scratch) {
  __shared__ int cnt[512];
  __shared__ int cur[512];
  __shared__ float degL[512];
  __shared__ float disL[512];
  __shared__ int ws[8];
  int bb = blockIdx.x;
  int t = threadIdx.x;
  if (bb >= Bg) {
    // ---- x-prefetch half: graph g lands in the XCD its score-readers use ----
    int g = (bb & 7) * 16 + ((bb - Bg) >> 3);     // bijective over 128 graphs
    const float4* xp4 = (const float4*)x + (size_t)g * NPG * 32;  // 512 rows x 32 f4
    float acc = 0.f;
    for (int i = t; i < NPG * 32; i += 512) {
      float4 v = xp4[i];
      acc += v.x + v.y + v.z + v.w;
    }
    scratch[(size_t)(bb - Bg) * 512 + t] = acc;   // keep loads live
    return;
  }
  int g = (bb & 7) * 16 + (bb >> 3);              // bijective, XCD-aligned
  int base = g * NPG;
  const int*   rowg  = row  + g * EPG;
  const int*   colg  = col  + g * EPG;
  const float* attrg = attr + g * EPG;
  cnt[t] = 0; degL[t] = 0.f;
  __syncthreads();
  for (int i = t; i < EPG; i += 512) {
    atomicAdd(&cnt[colg[i] - base], 1);
    atomicAdd(&degL[rowg[i] - base], attrg[i]);
  }
  __syncthreads();
  float d = degL[t];
  disL[t] = (d > 0.f) ? rsqrtf(fmaxf(d, 1e-12f)) : 0.f;
  scan512(cnt, ws);
  offs[base + t] = g * EPG + cnt[t];
  if (t == 0) offs[base + NPG] = g * EPG + EPG;
  cur[t] = cnt[t];
  __syncthreads();
  for (int i = t; i < EPG; i += 512) {
    int s = rowg[i] - base, c = colg[i] - base;
    int slot = atomicAdd(&cur[c], 1);
    int2 p;
    p.x = rowg[i] << 9;                            // src * 512 B (fp32 row stride)
    p.y = __float_as_int(disL[s] * attrg[i] * disL[c]);
    csrp[g * EPG + slot] = p;
  }
}

// ---------- K2: score gather + new_row/new_col streaming fill ----------
// One wave per node (wave-uniform CSR walk -> scalar index loads).
// Gather is L1-miss/latency-bound with idle write BW; each wave also
// streams one pooled row's new_row/new_col pattern (hidden under stalls).
__global__ __launch_bounds__(256) void k_score(const float* __restrict__ x,
                                               const int* __restrict__ offs,
                                               const int2* __restrict__ csrp,
                                               float* __restrict__ score,
                                               float* __restrict__ nrow,
                                               float* __restrict__ ncol) {
  int bb = blockIdx.x;
  int lane = threadIdx.x & 63;
  int w4 = threadIdx.x >> 6;

  // --- independent: new_row/new_col fill for pooled row `wid` ---
  int wid = bb * 4 + w4;
  if (wid < NKk) {
    int b = wid / Kk;
    float frow  = (float)wid;
    float cbase = (float)(b * Kk);
    size_t fb = (size_t)wid * Kk;
    f2v* nr = (f2v*)(nrow + fb);
    f2v* nc = (f2v*)(ncol + fb);
    for (int p = lane; p < Kk / 2; p += 64) {
      int j = 2 * p;
      f2v rv; rv.x = frow; rv.y = frow;
      f2v cv; cv.x = cbase + j; cv.y = cbase + j + 1;
      __builtin_nontemporal_store(rv, nr + p);
      __builtin_nontemporal_store(cv, nc + p);
    }
  }

  // --- gather ---
  int wg = ((bb & 7) << 11) | (bb >> 3);          // XCD-chunked swizzle
  int node = wg * 4 + w4;
  const char* xb = (const char*)x;
  int lo8 = lane * 8;
  float2 xv = *(const float2*)(xb + ((size_t)node << 9) + lo8);
  int s0 = offs[node], s1 = offs[node + 1];
  float a0 = 0.f, a1 = 0.f, b0 = 0.f, b1 = 0.f;
  int s = s0;
  for (; s + 4 <= s1; s += 4) {
    int2 p0 = csrp[s], p1 = csrp[s+1], p2 = csrp[s+2], p3 = csrp[s+3];
    float2 v0 = *(const float2*)(xb + p0.x + lo8);
    float2 v1 = *(const float2*)(xb + p1.x + lo8);
    float2 v2 = *(const float2*)(xb + p2.x + lo8);
    float2 v3 = *(const float2*)(xb + p3.x + lo8);
    float c0 = __int_as_float(p0.y), c1 = __int_as_float(p1.y);
    float c2 = __int_as_float(p2.y), c3 = __int_as_float(p3.y);
    a0 += c0 * v0.x; a1 += c0 * v0.y;
    b0 += c1 * v1.x; b1 += c1 * v1.y;
    a0 += c2 * v2.x; a1 += c2 * v2.y;
    b0 += c3 * v3.x; b1 += c3 * v3.y;
  }
  for (; s < s1; ++s) {
    int2 p0 = csrp[s];
    float2 v0 = *(const float2*)(xb + p0.x + lo8);
    float c0 = __int_as_float(p0.y);
    a0 += c0 * v0.x; a1 += c0 * v0.y;
  }
  float v = fabsf(xv.x - a0 - b0) + fabsf(xv.y - a1 - b1);
  #pragma unroll
  for (int d = 32; d; d >>= 1) v += __shfl_xor(v, d, 64);
  if (lane == 0) score[node] = v;
}

// ---------- K3: per-graph {stable top-k bitonic, perm/batch, induced CSR} ----------
__global__ __launch_bounds__(512) void k_topk_induced(const float* __restrict__ score,
                                                      const int* __restrict__ row,
                                                      const int* __restrict__ col,
                                                      const float* __restrict__ attr,
                                                      int* __restrict__ perm,
                                                      float* __restrict__ batch_out,
                                                      int* __restrict__ roffs,
                                                      int* __restrict__ icol,
                                                      float* __restrict__ ival) {
  __shared__ unsigned long long keys[512];
  __shared__ int mapL[512];
  __shared__ int rcnt[512];
  __shared__ int rcur[512];
  __shared__ int ws[8];
  int bb = blockIdx.x;
  int g = (bb & 7) * 16 + (bb >> 3);
  int t = threadIdx.x, base = g * NPG;
  float sc = score[base + t];
  unsigned u = __float_as_uint(sc);
  unsigned ord = (u & 0x80000000u) ? ~u : (u | 0x80000000u);
  keys[t] = ((unsigned long long)(~ord) << 32) | (unsigned)t;
  for (int k2 = 2; k2 <= 512; k2 <<= 1) {
    for (int j2 = k2 >> 1; j2 > 0; j2 >>= 1) {
      __syncthreads();
      int ixj = t ^ j2;
      if (ixj > t) {
        unsigned long long a = keys[t], b = keys[ixj];
        bool up = ((t & k2) == 0);
        if ((a > b) == up) { keys[t] = b; keys[ixj] = a; }
      }
    }
  }
  __syncthreads();
  int local = (int)(keys[t] & 0xFFFFFFFFu);
  mapL[local] = (t < Kk) ? t : -1;
  if (t < Kk) {
    perm[g * Kk + t] = base + local;
    batch_out[g * Kk + t] = (float)g;
  }
  rcnt[t] = 0;
  __syncthreads();
  const int*   rowg  = row  + g * EPG;
  const int*   colg  = col  + g * EPG;
  const float* attrg = attr + g * EPG;
  for (int i = t; i < EPG; i += 512) {
    int mr = mapL[rowg[i] - base], mc = mapL[colg[i] - base];
    if (mr >= 0 && mc >= 0) atomicAdd(&rcnt[mr], 1);
  }
  __syncthreads();
  scan512(rcnt, ws);
  if (t <= Kk) roffs[g * ROFFS_STRIDE + t] = g * EPG + rcnt[t];
  rcur[t] = rcnt[t];
  __syncthreads();
  for (int i = t; i < EPG; i += 512) {
    int mr = mapL[rowg[i] - base], mc = mapL[colg[i] - base];
    if (mr >= 0 && mc >= 0) {
      int slot = atomicAdd(&rcur[mr], 1);
      icol[g * EPG + slot] = mc;
      ival[g * EPG + slot] = attrg[i];
    }
  }
}

// ---------- K4: x_pool gather + e1/e2 GEMV, graph-aligned blocks ----------
__global__ __launch_bounds__(256) void k_feat(const float* __restrict__ x,
                                              const int* __restrict__ perm,
                                              const float* __restrict__ att,
                                              float* __restrict__ e1,
                                              float* __restrict__ e2,
                                              float* __restrict__ xpool) {
  int bb = blockIdx.x;
  int x8 = bb & 7, q = bb >> 3;
  int g = x8 * 16 + q / GPB;
  int blk = q % GPB;
  int lane = threadIdx.x & 63, w = threadIdx.x >> 6;
  int r = blk * 4 + w;
  if (r >= Kk) return;
  int j = g * Kk + r;
  int gsrc = perm[j];
  float2 xv = ((const float2*)x)[(size_t)gsrc * 64 + lane];
  ((float2*)xpool)[(size_t)j * 64 + lane] = xv;
  float2 a1 = ((const float2*)att)[lane];
  float2 a2 = ((const float2*)(att + Cc))[lane];
  float s1 = xv.x * a1.x + xv.y * a1.y;
  float s2 = xv.x * a2.x + xv.y * a2.y;
  #pragma unroll
  for (int d = 32; d; d >>= 1) { s1 += __shfl_xor(s1, d, 64); s2 += __shfl_xor(s2, d, 64); }
  if (lane == 0) { e1[j] = s1; e2[j] = s2; }
}

// ---------- K5: softmax, graph-aligned blocks, e2 in LDS, attn-only stores ----------
__global__ __launch_bounds__(256) void k_softmax(const float* __restrict__ e1,
                                                 const float* __restrict__ e2,
                                                 const int* __restrict__ roffs,
                                                 const int* __restrict__ icol,
                                                 const float* __restrict__ ival,
                                                 float* __restrict__ attn) {
  __shared__ float e2s[412];
  __shared__ float buf[4][416];
  int bb = blockIdx.x;
  int x8 = bb & 7, q = bb >> 3;
  int g = x8 * 16 + q / GPB;
  int blk = q % GPB;
  int t = threadIdx.x, lane = t & 63, w = t >> 6;
  for (int i = t; i < Kk; i += 256) e2s[i] = e2[g * Kk + i];
  __syncthreads();
  int r = blk * 4 + w;
  if (r >= Kk) return;
  int rowid = g * Kk + r;
  float* bw = buf[w];
  float ev = e1[rowid];
  for (int j = lane; j < Kk; j += 64) {
    float v = ev + e2s[j];
    bw[j] = (v > 0.f) ? v : SLOPE * v;
  }
  int t0 = roffs[g * ROFFS_STRIDE + r], t1 = roffs[g * ROFFS_STRIDE + r + 1];
  for (int p = t0 + lane; p < t1; p += 64)
    atomicAdd(&bw[icol[p]], ival[p]);              // LAMB = 1.0
  float m = -1e30f;
  for (int j = lane; j < Kk; j += 64) m = fmaxf(m, bw[j]);
  #pragma unroll
  for (int d = 32; d; d >>= 1) m = fmaxf(m, __shfl_xor(m, d, 64));
  float s = 0.f;
  for (int j = lane; j < Kk; j += 64) {
    float ex = __expf(bw[j] - m);
    bw[j] = ex;
    s += ex;
  }
  #pragma unroll
  for (int d = 32; d; d >>= 1) s += __shfl_xor(s, d, 64);
  float inv = 1.f / s;
  size_t fb = (size_t)rowid * Kk;
  f2v* ap = (f2v*)(attn + fb);
  for (int p = lane; p < Kk / 2; p += 64) {
    int j = 2 * p;
    f2v av; av.x = bw[j] * inv; av.y = bw[j + 1] * inv;
    __builtin_nontemporal_store(av, ap + p);
  }
}

// ---------------- host launch ----------------
extern "C" void kernel_launch(void* const* d_in, const int* in_sizes, int n_in,
                              void* d_out, int out_size, void* d_ws, size_t ws_size,
                              hipStream_t stream) {
  const float* x    = (const float*)d_in[0];
  const int*   row  = (const int*)d_in[1];
  const int*   col  = row + Ee;
  const float* attr = (const float*)d_in[2];
  const float* att  = (const float*)d_in[4];

  char* ws = (char*)d_ws;
  size_t off = 0;
  auto alloc = [&](size_t bytes) { char* p = ws + off; off = (off + bytes + 255) & ~(size_t)255; return p; };
  int*   offs     = (int*)  alloc((size_t)(Nn + 1) * 4);
  int2*  csrp     = (int2*) alloc((size_t)Ee * 8);
  float* score    = (float*)alloc((size_t)Nn * 4);
  int*   perm     = (int*)  alloc((size_t)NKk * 4);
  int*   roffs    = (int*)  alloc((size_t)Bg * ROFFS_STRIDE * 4);
  int*   icol     = (int*)  alloc((size_t)Ee * 4);
  float* ival     = (float*)alloc((size_t)Ee * 4);
  float* e1       = (float*)alloc((size_t)NKk * 4);
  float* e2       = (float*)alloc((size_t)NKk * 4);
  float* scratch  = (float*)alloc((size_t)Bg * 512 * 4);   // prefetch keep-live sink

  // output layout: x_pool | new_row | new_col | attn | batch_pool (all fp32)
  float* out      = (float*)d_out;
  float* o_xpool  = out;
  float* o_nrow   = o_xpool + (size_t)NKk * Cc;
  float* o_ncol   = o_nrow + (size_t)NKk * Kk;
  float* o_attn   = o_ncol + (size_t)NKk * Kk;
  float* o_batch  = o_attn + (size_t)NKk * Kk;

  k_build_csr  <<<Bg * 2,   512, 0, stream>>>(row, col, attr, x, offs, csrp, scratch);
  k_score      <<<Nn / 4,   256, 0, stream>>>(x, offs, csrp, score, o_nrow, o_ncol);
  k_topk_induced<<<Bg,      512, 0, stream>>>(score, row, col, attr, perm, o_batch, roffs, icol, ival);
  k_feat       <<<Bg * GPB, 256, 0, stream>>>(x, perm, att, e1, e2, o_xpool);
  k_softmax    <<<Bg * GPB, 256, 0, stream>>>(e1, e2, roffs, icol, ival, o_attn);
}

// Round 20
// 153.252 us; speedup vs baseline: 8.8840x; 1.0336x over previous
//
#include <hip/hip_runtime.h>
#include <stdint.h>

// Problem constants (from reference setup_inputs)
#define Bg    128
#define NPG   512
#define Cc    128
#define EPG   8192
#define Nn    (Bg*NPG)      // 65536
#define Ee    (Bg*EPG)      // 1048576
#define Kk    410           // ceil(0.8*512)
#define NKk   (Bg*Kk)       // 52480
#define ROFFS_STRIDE 411
#define SLOPE 0.2f
#define GPB   103           // graph-aligned blocks per graph for feat/softmax

typedef float f2v __attribute__((ext_vector_type(2)));

// ---------- exclusive scan over 512 ints, callable from 1024-thread block ----------
// threads >=512 participate in barriers only (guarded loads/stores).
__device__ __forceinline__ void scan512_b1024(int* buf, int* ws) {
  int t = threadIdx.x, lane = t & 63, w = t >> 6;
  int v = (t < 512) ? buf[t] : 0;
  int s = v;
  #pragma unroll
  for (int d = 1; d < 64; d <<= 1) { int u = __shfl_up(s, d, 64); if (lane >= d) s += u; }
  if (t < 512 && lane == 63) ws[w] = s;
  __syncthreads();
  if (t < 8) {
    int u = ws[t];
    #pragma unroll
    for (int d = 1; d < 8; d <<= 1) { int u2 = __shfl_up(u, d, 64); if (t >= d) u += u2; }
    ws[t] = u;
  }
  __syncthreads();
  if (t < 512) buf[t] = s - v + (w ? ws[w - 1] : 0);
  __syncthreads();
}

// ---------- K1: per-graph {deg, dis, count, scan, packed dst-CSR}, 1024 thr ----------
// R15 diag: 512-thr version was 19us at 12% occupancy (half machine idle,
// 8 waves/CU, latency-bound edge streams). 1024 thr doubles wave-parallelism
// of the two EPG-edge passes; 512-wide node phases guard t<512.
__global__ __launch_bounds__(1024) void k_build_csr(const int* __restrict__ row,
                                                    const int* __restrict__ col,
                                                    const float* __restrict__ attr,
                                                    int* __restrict__ offs,
                                                    int2* __restrict__ csrp) {
  __shared__ int cnt[512];
  __shared__ int cur[512];
  __shared__ float degL[512];
  __shared__ float disL[512];
  __shared__ int ws[8];
  int bb = blockIdx.x;
  int g = (bb & 7) * 16 + (bb >> 3);              // bijective, XCD-aligned
  int t = threadIdx.x, base = g * NPG;
  const int*   rowg  = row  + g * EPG;
  const int*   colg  = col  + g * EPG;
  const float* attrg = attr + g * EPG;
  if (t < 512) { cnt[t] = 0; degL[t] = 0.f; }
  __syncthreads();
  for (int i = t; i < EPG; i += 1024) {
    atomicAdd(&cnt[colg[i] - base], 1);
    atomicAdd(&degL[rowg[i] - base], attrg[i]);
  }
  __syncthreads();
  if (t < 512) {
    float d = degL[t];
    disL[t] = (d > 0.f) ? rsqrtf(fmaxf(d, 1e-12f)) : 0.f;
  }
  scan512_b1024(cnt, ws);
  if (t < 512) {
    offs[base + t] = g * EPG + cnt[t];
    cur[t] = cnt[t];
  }
  if (t == 0) offs[base + NPG] = g * EPG + EPG;
  __syncthreads();
  for (int i = t; i < EPG; i += 1024) {
    int s = rowg[i] - base, c = colg[i] - base;
    int slot = atomicAdd(&cur[c], 1);
    int2 p;
    p.x = rowg[i] << 9;                            // src * 512 B (fp32 row stride)
    p.y = __float_as_int(disL[s] * attrg[i] * disL[c]);
    csrp[g * EPG + slot] = p;
  }
}

// ---------- K2: score gather + new_row/new_col streaming fill ----------
// One wave per node (wave-uniform CSR walk -> scalar index loads).
// Gather is L1-miss/latency-bound with idle write BW; each wave also
// streams one pooled row's new_row/new_col pattern (R15: rides free).
__global__ __launch_bounds__(256) void k_score(const float* __restrict__ x,
                                               const int* __restrict__ offs,
                                               const int2* __restrict__ csrp,
                                               float* __restrict__ score,
                                               float* __restrict__ nrow,
                                               float* __restrict__ ncol) {
  int bb = blockIdx.x;
  int lane = threadIdx.x & 63;
  int w4 = threadIdx.x >> 6;

  // --- independent: new_row/new_col fill for pooled row `wid` ---
  int wid = bb * 4 + w4;
  if (wid < NKk) {
    int b = wid / Kk;
    float frow  = (float)wid;
    float cbase = (float)(b * Kk);
    size_t fb = (size_t)wid * Kk;
    f2v* nr = (f2v*)(nrow + fb);
    f2v* nc = (f2v*)(ncol + fb);
    for (int p = lane; p < Kk / 2; p += 64) {
      int j = 2 * p;
      f2v rv; rv.x = frow; rv.y = frow;
      f2v cv; cv.x = cbase + j; cv.y = cbase + j + 1;
      __builtin_nontemporal_store(rv, nr + p);
      __builtin_nontemporal_store(cv, nc + p);
    }
  }

  // --- gather ---
  int wg = ((bb & 7) << 11) | (bb >> 3);          // XCD-chunked swizzle
  int node = wg * 4 + w4;
  const char* xb = (const char*)x;
  int lo8 = lane * 8;
  float2 xv = *(const float2*)(xb + ((size_t)node << 9) + lo8);
  int s0 = offs[node], s1 = offs[node + 1];
  float a0 = 0.f, a1 = 0.f, b0 = 0.f, b1 = 0.f;
  int s = s0;
  for (; s + 4 <= s1; s += 4) {
    int2 p0 = csrp[s], p1 = csrp[s+1], p2 = csrp[s+2], p3 = csrp[s+3];
    float2 v0 = *(const float2*)(xb + p0.x + lo8);
    float2 v1 = *(const float2*)(xb + p1.x + lo8);
    float2 v2 = *(const float2*)(xb + p2.x + lo8);
    float2 v3 = *(const float2*)(xb + p3.x + lo8);
    float c0 = __int_as_float(p0.y), c1 = __int_as_float(p1.y);
    float c2 = __int_as_float(p2.y), c3 = __int_as_float(p3.y);
    a0 += c0 * v0.x; a1 += c0 * v0.y;
    b0 += c1 * v1.x; b1 += c1 * v1.y;
    a0 += c2 * v2.x; a1 += c2 * v2.y;
    b0 += c3 * v3.x; b1 += c3 * v3.y;
  }
  for (; s < s1; ++s) {
    int2 p0 = csrp[s];
    float2 v0 = *(const float2*)(xb + p0.x + lo8);
    float c0 = __int_as_float(p0.y);
    a0 += c0 * v0.x; a1 += c0 * v0.y;
  }
  float v = fabsf(xv.x - a0 - b0) + fabsf(xv.y - a1 - b1);
  #pragma unroll
  for (int d = 32; d; d >>= 1) v += __shfl_xor(v, d, 64);
  if (lane == 0) score[node] = v;
}

// ---------- K3: per-graph {stable top-k bitonic, perm/batch, induced CSR}, 1024 thr ----------
__global__ __launch_bounds__(1024) void k_topk_induced(const float* __restrict__ score,
                                                       const int* __restrict__ row,
                                                       const int* __restrict__ col,
                                                       const float* __restrict__ attr,
                                                       int* __restrict__ perm,
                                                       float* __restrict__ batch_out,
                                                       int* __restrict__ roffs,
                                                       int* __restrict__ icol,
                                                       float* __restrict__ ival) {
  __shared__ unsigned long long keys[512];
  __shared__ int mapL[512];
  __shared__ int rcnt[512];
  __shared__ int rcur[512];
  __shared__ int ws[8];
  int bb = blockIdx.x;
  int g = (bb & 7) * 16 + (bb >> 3);
  int t = threadIdx.x, base = g * NPG;
  if (t < 512) {
    float sc = score[base + t];
    unsigned u = __float_as_uint(sc);
    unsigned ord = (u & 0x80000000u) ? ~u : (u | 0x80000000u);
    keys[t] = ((unsigned long long)(~ord) << 32) | (unsigned)t;
  }
  for (int k2 = 2; k2 <= 512; k2 <<= 1) {
    for (int j2 = k2 >> 1; j2 > 0; j2 >>= 1) {
      __syncthreads();
      if (t < 512) {
        int ixj = t ^ j2;
        if (ixj > t) {
          unsigned long long a = keys[t], b = keys[ixj];
          bool up = ((t & k2) == 0);
          if ((a > b) == up) { keys[t] = b; keys[ixj] = a; }
        }
      }
    }
  }
  __syncthreads();
  if (t < 512) {
    int local = (int)(keys[t] & 0xFFFFFFFFu);
    mapL[local] = (t < Kk) ? t : -1;
    if (t < Kk) {
      perm[g * Kk + t] = base + local;
      batch_out[g * Kk + t] = (float)g;
    }
    rcnt[t] = 0;
  }
  __syncthreads();
  const int*   rowg  = row  + g * EPG;
  const int*   colg  = col  + g * EPG;
  const float* attrg = attr + g * EPG;
  for (int i = t; i < EPG; i += 1024) {
    int mr = mapL[rowg[i] - base], mc = mapL[colg[i] - base];
    if (mr >= 0 && mc >= 0) atomicAdd(&rcnt[mr], 1);
  }
  __syncthreads();
  scan512_b1024(rcnt, ws);
  if (t <= Kk) roffs[g * ROFFS_STRIDE + t] = g * EPG + rcnt[t];
  if (t < 512) rcur[t] = rcnt[t];
  __syncthreads();
  for (int i = t; i < EPG; i += 1024) {
    int mr = mapL[rowg[i] - base], mc = mapL[colg[i] - base];
    if (mr >= 0 && mc >= 0) {
      int slot = atomicAdd(&rcur[mr], 1);
      icol[g * EPG + slot] = mc;
      ival[g * EPG + slot] = attrg[i];
    }
  }
}

// ---------- K4: x_pool gather + e1/e2 GEMV, graph-aligned blocks ----------
__global__ __launch_bounds__(256) void k_feat(const float* __restrict__ x,
                                              const int* __restrict__ perm,
                                              const float* __restrict__ att,
                                              float* __restrict__ e1,
                                              float* __restrict__ e2,
                                              float* __restrict__ xpool) {
  int bb = blockIdx.x;
  int x8 = bb & 7, q = bb >> 3;
  int g = x8 * 16 + q / GPB;
  int blk = q % GPB;
  int lane = threadIdx.x & 63, w = threadIdx.x >> 6;
  int r = blk * 4 + w;
  if (r >= Kk) return;
  int j = g * Kk + r;
  int gsrc = perm[j];
  float2 xv = ((const float2*)x)[(size_t)gsrc * 64 + lane];
  ((float2*)xpool)[(size_t)j * 64 + lane] = xv;
  float2 a1 = ((const float2*)att)[lane];
  float2 a2 = ((const float2*)(att + Cc))[lane];
  float s1 = xv.x * a1.x + xv.y * a1.y;
  float s2 = xv.x * a2.x + xv.y * a2.y;
  #pragma unroll
  for (int d = 32; d; d >>= 1) { s1 += __shfl_xor(s1, d, 64); s2 += __shfl_xor(s2, d, 64); }
  if (lane == 0) { e1[j] = s1; e2[j] = s2; }
}

// ---------- K5: softmax, graph-aligned blocks, e2 in LDS, attn-only stores ----------
__global__ __launch_bounds__(256) void k_softmax(const float* __restrict__ e1,
                                                 const float* __restrict__ e2,
                                                 const int* __restrict__ roffs,
                                                 const int* __restrict__ icol,
                                                 const float* __restrict__ ival,
                                                 float* __restrict__ attn) {
  __shared__ float e2s[412];
  __shared__ float buf[4][416];
  int bb = blockIdx.x;
  int x8 = bb & 7, q = bb >> 3;
  int g = x8 * 16 + q / GPB;
  int blk = q % GPB;
  int t = threadIdx.x, lane = t & 63, w = t >> 6;
  for (int i = t; i < Kk; i += 256) e2s[i] = e2[g * Kk + i];
  __syncthreads();
  int r = blk * 4 + w;
  if (r >= Kk) return;
  int rowid = g * Kk + r;
  float* bw = buf[w];
  float ev = e1[rowid];
  for (int j = lane; j < Kk; j += 64) {
    float v = ev + e2s[j];
    bw[j] = (v > 0.f) ? v : SLOPE * v;
  }
  int t0 = roffs[g * ROFFS_STRIDE + r], t1 = roffs[g * ROFFS_STRIDE + r + 1];
  for (int p = t0 + lane; p < t1; p += 64)
    atomicAdd(&bw[icol[p]], ival[p]);              // LAMB = 1.0
  float m = -1e30f;
  for (int j = lane; j < Kk; j += 64) m = fmaxf(m, bw[j]);
  #pragma unroll
  for (int d = 32; d; d >>= 1) m = fmaxf(m, __shfl_xor(m, d, 64));
  float s = 0.f;
  for (int j = lane; j < Kk; j += 64) {
    float ex = __expf(bw[j] - m);
    bw[j] = ex;
    s += ex;
  }
  #pragma unroll
  for (int d = 32; d; d >>= 1) s += __shfl_xor(s, d, 64);
  float inv = 1.f / s;
  size_t fb = (size_t)rowid * Kk;
  f2v* ap = (f2v*)(attn + fb);
  for (int p = lane; p < Kk / 2; p += 64) {
    int j = 2 * p;
    f2v av; av.x = bw[j] * inv; av.y = bw[j + 1] * inv;
    __builtin_nontemporal_store(av, ap + p);
  }
}

// ---------------- host launch ----------------
extern "C" void kernel_launch(void* const* d_in, const int* in_sizes, int n_in,
                              void* d_out, int out_size, void* d_ws, size_t ws_size,
                              hipStream_t stream) {
  const float* x    = (const float*)d_in[0];
  const int*   row  = (const int*)d_in[1];
  const int*   col  = row + Ee;
  const float* attr = (const float*)d_in[2];
  const float* att  = (const float*)d_in[4];

  char* ws = (char*)d_ws;
  size_t off = 0;
  auto alloc = [&](size_t bytes) { char* p = ws + off; off = (off + bytes + 255) & ~(size_t)255; return p; };
  int*   offs     = (int*)  alloc((size_t)(Nn + 1) * 4);
  int2*  csrp     = (int2*) alloc((size_t)Ee * 8);
  float* score    = (float*)alloc((size_t)Nn * 4);
  int*   perm     = (int*)  alloc((size_t)NKk * 4);
  int*   roffs    = (int*)  alloc((size_t)Bg * ROFFS_STRIDE * 4);
  int*   icol     = (int*)  alloc((size_t)Ee * 4);
  float* ival     = (float*)alloc((size_t)Ee * 4);
  float* e1       = (float*)alloc((size_t)NKk * 4);
  float* e2       = (float*)alloc((size_t)NKk * 4);

  // output layout: x_pool | new_row | new_col | attn | batch_pool (all fp32)
  float* out      = (float*)d_out;
  float* o_xpool  = out;
  float* o_nrow   = o_xpool + (size_t)NKk * Cc;
  float* o_ncol   = o_nrow + (size_t)NKk * Kk;
  float* o_attn   = o_ncol + (size_t)NKk * Kk;
  float* o_batch  = o_attn + (size_t)NKk * Kk;

  k_build_csr  <<<Bg,       1024, 0, stream>>>(row, col, attr, offs, csrp);
  k_score      <<<Nn / 4,   256,  0, stream>>>(x, offs, csrp, score, o_nrow, o_ncol);
  k_topk_induced<<<Bg,      1024, 0, stream>>>(score, row, col, attr, perm, o_batch, roffs, icol, ival);
  k_feat       <<<Bg * GPB, 256,  0, stream>>>(x, perm, att, e1, e2, o_xpool);
  k_softmax    <<<Bg * GPB, 256,  0, stream>>>(e1, e2, roffs, icol, ival, o_attn);
}